// Round 8
// baseline (1294.878 us; speedup 1.0000x reference)
//
#include <hip/hip_runtime.h>
#include <math.h>

#define BB 8
#define TT 512
#define HH 8
#define ESS 96
#define EMBD 768
#define FFD 3072
#define NLAYER 6
#define KHMAX 576   // 96 * 6, history feature pitch

typedef unsigned short ushort_t;
typedef __attribute__((ext_vector_type(8))) short short8;
typedef __attribute__((ext_vector_type(4))) float f32x4;
typedef __attribute__((ext_vector_type(4))) unsigned short ushort4v;

static __device__ __forceinline__ ushort_t f2b(float f) {
    unsigned u = __builtin_bit_cast(unsigned, f);
    unsigned r = (u + 0x7fffu + ((u >> 16) & 1u)) >> 16;
    return (ushort_t)r;
}

#define GLDS(gp, lp) __builtin_amdgcn_global_load_lds( \
    (const __attribute__((address_space(1))) void*)(gp), \
    (__attribute__((address_space(3))) void*)(lp), 16, 0, 0)

// ---------------------------------------------------------------------------
// bf16 MFMA GEMM: C = alpha * A(M,K) * B(N,K)^T (+beta*C) (+bias) (+gelu)
// ---------------------------------------------------------------------------
template<int BM, int BN, int WM, int WN, int OUTBF, int HASBIAS, int GELU, int BETA>
__global__ __launch_bounds__(256) void gemm_mfma(
    const ushort_t* __restrict__ A, int lda,
    const ushort_t* __restrict__ B, int ldb,
    void* __restrict__ Cv, int ldc,
    int K, float alpha,
    const float* __restrict__ bias,
    int bdiv, long sAb, long sAh, long sBb, long sBh, long sCb, long sCh)
{
    constexpr int BK = 32;
    constexpr int WTM = BM / WM;
    constexpr int WTN = BN / WN;
    constexpr int MF = WTM / 16, NF = WTN / 16;
    constexpr int ACH = (BM * BK * 2) / 1024;
    constexpr int BCH = (BN * BK * 2) / 1024;

    const int z = blockIdx.z;
    const int zb = z / bdiv, zh = z % bdiv;
    A += (long)zb * sAb + (long)zh * sAh;
    B += (long)zb * sBb + (long)zh * sBh;
    const long coff = (long)zb * sCb + (long)zh * sCh;

    __shared__ ushort_t As[BM * BK];
    __shared__ ushort_t Bs[BN * BK];

    const int tid = threadIdx.x;
    const int w = tid >> 6, lane = tid & 63;
    const int wr = w / WN, wc = w % WN;
    const int m0 = blockIdx.y * BM;
    const int n0 = blockIdx.x * BN;

    f32x4 acc[MF][NF] = {};

    const int fr = lane & 15;
    const int kb = lane >> 4;

    for (int k0 = 0; k0 < K; k0 += BK) {
#pragma unroll
        for (int q = 0; q < (ACH + 3) / 4; ++q) {
            int ci = q * 4 + w;
            if (ci < ACH) {
                int e = ci * 512 + lane * 8;
                int r = e >> 5, c = e & 31;
                GLDS(A + (long)(m0 + r) * lda + (k0 + c), (char*)As + ci * 1024);
            }
        }
#pragma unroll
        for (int q = 0; q < (BCH + 3) / 4; ++q) {
            int ci = q * 4 + w;
            if (ci < BCH) {
                int e = ci * 512 + lane * 8;
                int r = e >> 5, c = e & 31;
                GLDS(B + (long)(n0 + r) * ldb + (k0 + c), (char*)Bs + ci * 1024);
            }
        }
        __syncthreads();

        short8 af[MF], bfr[NF];
#pragma unroll
        for (int fm = 0; fm < MF; ++fm)
            af[fm] = *(const short8*)&As[(wr * WTM + fm * 16 + fr) * 32 + kb * 8];
#pragma unroll
        for (int fn = 0; fn < NF; ++fn)
            bfr[fn] = *(const short8*)&Bs[(wc * WTN + fn * 16 + fr) * 32 + kb * 8];
#pragma unroll
        for (int fm = 0; fm < MF; ++fm)
#pragma unroll
            for (int fn = 0; fn < NF; ++fn)
                acc[fm][fn] = __builtin_amdgcn_mfma_f32_16x16x32_bf16(
                    af[fm], bfr[fn], acc[fm][fn], 0, 0, 0);
        __syncthreads();
    }

    const int cr = lane >> 4;
    const int cc = lane & 15;
#pragma unroll
    for (int fm = 0; fm < MF; ++fm) {
#pragma unroll
        for (int fn = 0; fn < NF; ++fn) {
#pragma unroll
            for (int j = 0; j < 4; ++j) {
                int gm = m0 + wr * WTM + fm * 16 + cr * 4 + j;
                int gn = n0 + wc * WTN + fn * 16 + cc;
                float v = alpha * acc[fm][fn][j];
                if (HASBIAS) v += bias[gn];
                if (GELU) v = 0.5f * v * (1.f + erff(v * 0.70710678118654752f));
                long idx = coff + (long)gm * ldc + gn;
                if (BETA) v += ((const float*)Cv)[idx];
                if (OUTBF) ((ushort_t*)Cv)[idx] = f2b(v);
                else       ((float*)Cv)[idx] = v;
            }
        }
    }
}

// ---------------------------------------------------------------------------
// Fused attention with Q/K-history accumulation (RealFormer carry).
// XCD-aware 1D grid (1024 blocks). Phase 3 (PV) is barrier-free: V^T
// fragments load global->register (L2-resident per XCD), P stays in LDS.
// ---------------------------------------------------------------------------
__global__ __launch_bounds__(256) void fused_attn(
    const ushort_t* __restrict__ Qh,    // (B*H, T, 576) bf16, cols [0,Kd)
    const ushort_t* __restrict__ Kh,    // (B*H, T, 576) bf16
    const ushort_t* __restrict__ Vt,    // (B*H, 96, T) bf16
    ushort_t* __restrict__ attn,        // (B,T,EMB) bf16
    float scale, int Kd)
{
    __shared__ char lds[40960];
    ushort_t* As = (ushort_t*)lds;              // 2 KiB: Q tile 32x32
    ushort_t* Bs = (ushort_t*)(lds + 2048);     // 32 KiB: K tile 512x32
    ushort_t* Pt = (ushort_t*)(lds + 2048);     // union: P 32x512 bf16 (swizzled)
    float* red   = (float*)(lds + 34816);       // 512 B
    float* red2  = (float*)(lds + 35328);       // 512 B
    ushort_t* Os = (ushort_t*)(lds + 34816);    // 6 KiB out tile (union red/red2)

    // XCD swizzle: hw xcd = wg & 7 (round-robin)
    const int wg = blockIdx.x;
    const int xcd = wg & 7;
    const int sub = wg >> 3;          // 0..127, sequential within an XCD
    const int m0 = (sub & 15) * 32;   // m-tile fastest -> same bh consecutive
    const int bh = (sub >> 4) * 8 + xcd;
    const int b = bh >> 3, h = bh & 7;

    const int tid = threadIdx.x;
    const int w = tid >> 6, lane = tid & 63;
    const int fr = lane & 15, kb = lane >> 4;
    const int cr = kb, cc = fr;

    f32x4 acc[2][8] = {};

    // ---- phase 1: S = Q_hist K_hist^T over Kd feature cols ----
    for (int k0 = 0; k0 < Kd; k0 += 32) {
        if (w < 2) {
            int e = w * 512 + lane * 8;
            int r = e >> 5, c = e & 31;
            GLDS(Qh + ((long)(bh * TT + m0 + r)) * KHMAX + k0 + c,
                 (char*)As + w * 1024);
        }
#pragma unroll
        for (int q = 0; q < 8; ++q) {
            int ci = q * 4 + w;
            int e = ci * 512 + lane * 8;
            int r = e >> 5, c = e & 31;
            GLDS(Kh + ((long)(bh * TT + r)) * KHMAX + k0 + c,
                 (char*)Bs + ci * 1024);
        }
        __syncthreads();
        short8 af[2];
        af[0] = *(const short8*)&As[fr * 32 + kb * 8];
        af[1] = *(const short8*)&As[(16 + fr) * 32 + kb * 8];
#pragma unroll
        for (int fn = 0; fn < 8; ++fn) {
            short8 bf = *(const short8*)&Bs[(w * 128 + fn * 16 + fr) * 32 + kb * 8];
            acc[0][fn] = __builtin_amdgcn_mfma_f32_16x16x32_bf16(af[0], bf, acc[0][fn], 0, 0, 0);
            acc[1][fn] = __builtin_amdgcn_mfma_f32_16x16x32_bf16(af[1], bf, acc[1][fn], 0, 0, 0);
        }
        __syncthreads();
    }

    // ---- phase 2: softmax over key axis ----
#pragma unroll
    for (int fm = 0; fm < 2; ++fm)
#pragma unroll
        for (int fn = 0; fn < 8; ++fn)
#pragma unroll
            for (int j = 0; j < 4; ++j)
                acc[fm][fn][j] *= scale;

#pragma unroll
    for (int fm = 0; fm < 2; ++fm)
#pragma unroll
        for (int j = 0; j < 4; ++j) {
            float mx = -1e30f;
#pragma unroll
            for (int fn = 0; fn < 8; ++fn) mx = fmaxf(mx, acc[fm][fn][j]);
            for (int o = 1; o <= 8; o <<= 1) mx = fmaxf(mx, __shfl_xor(mx, o));
            if (cc == 0) red[w * 32 + fm * 16 + cr * 4 + j] = mx;
        }
    __syncthreads();

    float inv[2][4];
#pragma unroll
    for (int fm = 0; fm < 2; ++fm)
#pragma unroll
        for (int j = 0; j < 4; ++j) {
            int r = fm * 16 + cr * 4 + j;
            float mx = fmaxf(fmaxf(red[r], red[32 + r]), fmaxf(red[64 + r], red[96 + r]));
            float s = 0.f;
#pragma unroll
            for (int fn = 0; fn < 8; ++fn) {
                float e = __expf(acc[fm][fn][j] - mx);
                acc[fm][fn][j] = e;
                s += e;
            }
            for (int o = 1; o <= 8; o <<= 1) s += __shfl_xor(s, o);
            if (cc == 0) red2[w * 32 + r] = s;
        }
    __syncthreads();
#pragma unroll
    for (int fm = 0; fm < 2; ++fm)
#pragma unroll
        for (int j = 0; j < 4; ++j) {
            int r = fm * 16 + cr * 4 + j;
            inv[fm][j] = 1.f / (red2[r] + red2[32 + r] + red2[64 + r] + red2[96 + r]);
        }
    __syncthreads();   // red/red2 fully read before Os overwrites the region

    // write P (bf16) into swizzled LDS tile (elem col ^= (row&7)<<3)
#pragma unroll
    for (int fm = 0; fm < 2; ++fm)
#pragma unroll
        for (int fn = 0; fn < 8; ++fn)
#pragma unroll
            for (int j = 0; j < 4; ++j) {
                int row = fm * 16 + cr * 4 + j;
                int col = w * 128 + fn * 16 + cc;
                Pt[row * 512 + (col ^ ((row & 7) << 3))] = f2b(acc[fm][fn][j] * inv[fm][j]);
            }
    __syncthreads();

    // ---- phase 3: attn = P @ V. Barrier-free: V^T direct global->reg ----
    const int wr = w >> 1, wc2 = w & 1;
    const ushort_t* Vbase = Vt + ((long)(bh * ESS + wc2 * 48 + fr)) * TT;
    const int prow = wr * 16 + fr;
    f32x4 po[3] = {};
    __builtin_amdgcn_s_setprio(1);
#pragma unroll
    for (int j0 = 0; j0 < TT; j0 += 32) {
        short8 pa = *(const short8*)&Pt[prow * 512 + ((j0 + kb * 8) ^ ((prow & 7) << 3))];
#pragma unroll
        for (int fn = 0; fn < 3; ++fn) {
            short8 vb = *(const short8*)&Vbase[(long)(fn * 16) * TT + j0 + kb * 8];
            po[fn] = __builtin_amdgcn_mfma_f32_16x16x32_bf16(pa, vb, po[fn], 0, 0, 0);
        }
    }
    __builtin_amdgcn_s_setprio(0);

    // stage output tile 32x96 to LDS, then coalesced u32 store
#pragma unroll
    for (int fn = 0; fn < 3; ++fn)
#pragma unroll
        for (int j = 0; j < 4; ++j)
            Os[(wr * 16 + cr * 4 + j) * ESS + wc2 * 48 + fn * 16 + cc] = f2b(po[fn][j]);
    __syncthreads();

    {
        const unsigned* Os32 = (const unsigned*)Os;
        const int row = tid >> 3, seg = tid & 7;
        unsigned* drow = (unsigned*)(attn + ((long)(b * TT + m0 + row)) * EMBD + h * ESS);
#pragma unroll
        for (int k = 0; k < 6; ++k)
            drow[seg * 6 + k] = Os32[row * 48 + seg * 6 + k];
    }
}

// ---------------------------------------------------------------------------
// Scatter kqv (B,T,H,288): V -> Vt[(bh,s),t] ; K,Q -> history col block loff
// ---------------------------------------------------------------------------
__global__ __launch_bounds__(256) void scatter_kqv(
    const ushort_t* __restrict__ kqv, ushort_t* __restrict__ Kh,
    ushort_t* __restrict__ Qh, ushort_t* __restrict__ Vt, int loff)
{
    const int bid = blockIdx.x;
    if (bid < 12288) {
        int idx = bid * 256 + threadIdx.x;       // (bh, s, t), consecutive t
        int t = idx & 511;
        int rest = idx >> 9;
        int s = rest % ESS;
        int bh = rest / ESS;
        int h = bh & 7, b = bh >> 3;
        Vt[idx] = kqv[((long)((b * TT + t) * HH + h)) * 288 + 192 + s];
    } else {
        int grp = (bid - 12288) / 12288;         // 0 = K, 1 = Q
        int idx = ((bid - 12288) % 12288) * 256 + threadIdx.x;  // (bh,t,s)
        int s = idx % ESS;
        int t2 = idx / ESS;
        int t = t2 & 511;
        int bh = t2 >> 9;
        int h = bh & 7, b = bh >> 3;
        ushort_t v = kqv[((long)((b * TT + t) * HH + h)) * 288 + grp * 96 + s];
        ushort_t* dst = grp ? Qh : Kh;
        dst[((long)(bh * TT + t)) * KHMAX + loff + s] = v;
    }
}

// ---------------------------------------------------------------------------
__global__ __launch_bounds__(256) void cvt_f2b(
    const float* __restrict__ in, ushort_t* __restrict__ out)
{
    const int i = blockIdx.x * 256 + threadIdx.x;
    float4 v = ((const float4*)in)[i];
    ushort4v o = {f2b(v.x), f2b(v.y), f2b(v.z), f2b(v.w)};
    ((ushort4v*)out)[i] = o;
}

// ---------------------------------------------------------------------------
// Weight conversion. Per-layer contiguous layout (float4/ushort4v units):
//   [wkqv 6912 | wproj 147456 | w1 589824 | w2 589824] = 1334016 per layer
// ---------------------------------------------------------------------------
static __device__ __forceinline__ void cvt_w_one(
    int r, int layer,
    const float* Wkqv, const float* Wproj, const float* w1, const float* w2,
    ushort_t* dst_layer)
{
    const float* src; int base;
    if (r < 6912)        { src = Wkqv  + (long)layer * 27648;   base = 0; }
    else if (r < 154368) { src = Wproj + (long)layer * 589824;  base = 6912; }
    else if (r < 744192) { src = w1    + (long)layer * 2359296; base = 154368; }
    else                 { src = w2    + (long)layer * 2359296; base = 744192; }
    int j = r - base;
    float4 v = ((const float4*)src)[j];
    ushort4v o = {f2b(v.x), f2b(v.y), f2b(v.z), f2b(v.w)};
    ((ushort4v*)dst_layer)[r] = o;
}

__global__ __launch_bounds__(256) void cvt_weights_all(
    const float* __restrict__ Wkqv, const float* __restrict__ Wproj,
    const float* __restrict__ w1, const float* __restrict__ w2,
    ushort_t* __restrict__ dst)      // 6 layers, stride 5336064 ushorts
{
    int i4 = blockIdx.x * 256 + threadIdx.x;    // 0 .. 8004095
    int layer = i4 / 1334016;
    int r = i4 - layer * 1334016;
    cvt_w_one(r, layer, Wkqv, Wproj, w1, w2, dst + (long)layer * 5336064);
}

__global__ __launch_bounds__(256) void cvt_weights_layer(
    const float* __restrict__ Wkqv, const float* __restrict__ Wproj,
    const float* __restrict__ w1, const float* __restrict__ w2,
    ushort_t* __restrict__ dst, int layer)      // one layer into dst
{
    int r = blockIdx.x * 256 + threadIdx.x;     // 0 .. 1334015
    cvt_w_one(r, layer, Wkqv, Wproj, w1, w2, dst);
}

// ---------------------------------------------------------------------------
// x = LayerNorm(x + r0 + r1 (+bias)) * g + b ; also emit bf16 copy.
// ---------------------------------------------------------------------------
__global__ __launch_bounds__(192) void add_ln(
    float* __restrict__ x, const float* __restrict__ r0,
    const float* __restrict__ r1, const float* __restrict__ bias,
    const float* __restrict__ g, const float* __restrict__ bta,
    ushort_t* __restrict__ xb)
{
    const long row = blockIdx.x;
    float4* xr = (float4*)(x + row * EMBD);
    const float4* q0 = (const float4*)(r0 + row * EMBD);
    const float4* q1 = (const float4*)(r1 + row * EMBD);
    __shared__ float sh[4];
    const int tid = threadIdx.x;
    const int lane = tid & 63, w = tid >> 6;

    float4 a = xr[tid], u0 = q0[tid], u1 = q1[tid];
    float v[4] = {a.x + u0.x + u1.x, a.y + u0.y + u1.y,
                  a.z + u0.z + u1.z, a.w + u0.w + u1.w};
    if (bias) {
        float4 b4 = ((const float4*)bias)[tid];
        v[0] += b4.x; v[1] += b4.y; v[2] += b4.z; v[3] += b4.w;
    }
    float s = v[0] + v[1] + v[2] + v[3];
    for (int o = 32; o; o >>= 1) s += __shfl_xor(s, o);
    if (lane == 0) sh[w] = s;
    __syncthreads();
    float mu = (sh[0] + sh[1] + sh[2]) * (1.f / EMBD);

    float var = 0.f;
#pragma unroll
    for (int c = 0; c < 4; ++c) { float d = v[c] - mu; var += d * d; }
    for (int o = 32; o; o >>= 1) var += __shfl_xor(var, o);
    __syncthreads();
    if (lane == 0) sh[w] = var;
    __syncthreads();
    var = (sh[0] + sh[1] + sh[2]) * (1.f / EMBD);
    float rstd = rsqrtf(var + 1e-5f);

    const float4 g4 = ((const float4*)g)[tid];
    const float4 b4 = ((const float4*)bta)[tid];
    float o0 = (v[0] - mu) * rstd * g4.x + b4.x;
    float o1 = (v[1] - mu) * rstd * g4.y + b4.y;
    float o2 = (v[2] - mu) * rstd * g4.z + b4.z;
    float o3 = (v[3] - mu) * rstd * g4.w + b4.w;
    float4 ov = {o0, o1, o2, o3};
    xr[tid] = ov;
    ushort4v ob = {f2b(o0), f2b(o1), f2b(o2), f2b(o3)};
    ((ushort4v*)(xb + row * EMBD))[tid] = ob;
}

// ---------------------------------------------------------------------------
extern "C" void kernel_launch(void* const* d_in, const int* in_sizes, int n_in,
                              void* d_out, int out_size, void* d_ws, size_t ws_size,
                              hipStream_t stream) {
    const float* x_in  = (const float*)d_in[0];
    const float* Wkqv  = (const float*)d_in[1];
    const float* Wproj = (const float*)d_in[2];
    const float* ln1_g = (const float*)d_in[3];
    const float* ln1_b = (const float*)d_in[4];
    const float* ln2_g = (const float*)d_in[5];
    const float* ln2_b = (const float*)d_in[6];
    const float* ff_w1 = (const float*)d_in[7];
    const float* ff_b1 = (const float*)d_in[8];
    const float* ff_w2 = (const float*)d_in[9];
    const float* ff_b2 = (const float*)d_in[10];

    float* x = (float*)d_out;
    char* ws = (char*)d_ws;
    ushort_t* Qh     = (ushort_t*)(ws);
    ushort_t* Kh     = (ushort_t*)(ws + 37748736);
    ushort_t* Vtb    = (ushort_t*)(ws + 75497472);
    ushort_t* kqvb   = (ushort_t*)(ws + 81788928);
    float*    res0   = (float*)(ws + 75497472);
    float*    res1   = (float*)(ws + 88080384);
    ushort_t* h1b    = (ushort_t*)(ws + 100663296);
    ushort_t* xb     = (ushort_t*)(ws + 125829120);
    ushort_t* attnb  = (ushort_t*)(ws + 132120576);
    ushort_t* Wall   = (ushort_t*)(ws + 138412032);
    const size_t WLAYER_B = 10672128;          // bytes per layer slot
    const int    WLAYER_E = 5336064;           // ushorts per layer slot
    const int big = (ws_size >= 138412032 + 6 * WLAYER_B) ? 1 : 0;

    hipMemcpyAsync(x, x_in, (size_t)BB * TT * EMBD * sizeof(float),
                   hipMemcpyDeviceToDevice, stream);
    cvt_f2b<<<3072, 256, 0, stream>>>(x_in, xb);
    if (big)
        cvt_weights_all<<<31266, 256, 0, stream>>>(Wkqv, Wproj, ff_w1, ff_w2, Wall);

    const float scale = 0.10206207261596577f;  // 1/sqrt(96)

    for (int l = 0; l < NLAYER; ++l) {
        const float* b1 = ff_b1 + (size_t)l * FFD;
        const float* b2 = ff_b2 + (size_t)l * EMBD;

        ushort_t* Wl = Wall + (big ? (long)l * WLAYER_E : 0);
        if (!big)
            cvt_weights_layer<<<5211, 256, 0, stream>>>(Wkqv, Wproj, ff_w1, ff_w2, Wl, l);
        ushort_t* Wkqvb  = Wl;
        ushort_t* Wprojb = Wl + 27648;
        ushort_t* W1b    = Wl + 617472;
        ushort_t* W2b    = Wl + 2976768;

        // kqv = xh @ wkqv^T  -> (B,T,H,288) bf16
        gemm_mfma<128, 96, 4, 1, 1, 0, 0, 0><<<dim3(3, 256, 1), 256, 0, stream>>>(
            xb, ESS, Wkqvb, ESS, kqvb, 288, ESS, 1.f, nullptr,
            1, 0, 0, 0, 0, 0, 0);

        // scatter: V -> Vt ; K,Q -> history col block l*96
        scatter_kqv<<<36864, 256, 0, stream>>>(kqvb, Kh, Qh, Vtb, l * ESS);

        // fused: S = scale * Qh Kh^T (Kd=96*(l+1)); attn = softmax(S) @ V
        fused_attn<<<1024, 256, 0, stream>>>(
            Qh, Kh, Vtb, attnb, scale, ESS * (l + 1));

        // res0/res1 = attn @ Wproj^T split-K
        gemm_mfma<128, 128, 2, 2, 0, 0, 0, 0><<<dim3(6, 32, 2), 256, 0, stream>>>(
            attnb, EMBD, Wprojb, EMBD, res0, EMBD, EMBD / 2, 1.f, nullptr,
            1, 384, 0, 384, 0, (long)(res1 - res0), 0);

        add_ln<<<BB * TT, 192, 0, stream>>>(x, res0, res1, nullptr,
            ln1_g + (size_t)l * EMBD, ln1_b + (size_t)l * EMBD, xb);

        // h1 = gelu(xb @ W1^T + b1)
        gemm_mfma<128, 128, 2, 2, 1, 1, 1, 0><<<dim3(24, 32, 1), 256, 0, stream>>>(
            xb, EMBD, W1b, EMBD, h1b, FFD, EMBD, 1.f, b1,
            1, 0, 0, 0, 0, 0, 0);

        // res0/res1 = h1 @ W2^T split-K (b2 applied in ln2)
        gemm_mfma<128, 128, 2, 2, 0, 0, 0, 0><<<dim3(6, 32, 2), 256, 0, stream>>>(
            h1b, FFD, W2b, FFD, res0, EMBD, FFD / 2, 1.f, nullptr,
            1, 1536, 0, 1536, 0, (long)(res1 - res0), 0);

        add_ln<<<BB * TT, 192, 0, stream>>>(x, res0, res1, b2,
            ln2_g + (size_t)l * EMBD, ln2_b + (size_t)l * EMBD, xb);
    }
}

// Round 9
// 1180.931 us; speedup vs baseline: 1.0965x; 1.0965x over previous
//
#include <hip/hip_runtime.h>
#include <math.h>

#define BB 8
#define TT 512
#define HH 8
#define ESS 96
#define EMBD 768
#define FFD 3072
#define NLAYER 6
#define KHMAX 576   // 96 * 6, history feature pitch

typedef unsigned short ushort_t;
typedef __attribute__((ext_vector_type(8))) short short8;
typedef __attribute__((ext_vector_type(4))) float f32x4;
typedef __attribute__((ext_vector_type(4))) unsigned short ushort4v;

static __device__ __forceinline__ ushort_t f2b(float f) {
    unsigned u = __builtin_bit_cast(unsigned, f);
    unsigned r = (u + 0x7fffu + ((u >> 16) & 1u)) >> 16;
    return (ushort_t)r;
}

#define GLDS(gp, lp) __builtin_amdgcn_global_load_lds( \
    (const __attribute__((address_space(1))) void*)(gp), \
    (__attribute__((address_space(3))) void*)(lp), 16, 0, 0)

// ---------------------------------------------------------------------------
// bf16 MFMA GEMM: C = alpha * A(M,K) * B(N,K)^T (+beta*C) (+bias) (+gelu)
// ---------------------------------------------------------------------------
template<int BM, int BN, int WM, int WN, int OUTBF, int HASBIAS, int GELU, int BETA>
__global__ __launch_bounds__(256) void gemm_mfma(
    const ushort_t* __restrict__ A, int lda,
    const ushort_t* __restrict__ B, int ldb,
    void* __restrict__ Cv, int ldc,
    int K, float alpha,
    const float* __restrict__ bias,
    int bdiv, long sAb, long sAh, long sBb, long sBh, long sCb, long sCh)
{
    constexpr int BK = 32;
    constexpr int WTM = BM / WM;
    constexpr int WTN = BN / WN;
    constexpr int MF = WTM / 16, NF = WTN / 16;
    constexpr int ACH = (BM * BK * 2) / 1024;
    constexpr int BCH = (BN * BK * 2) / 1024;

    const int z = blockIdx.z;
    const int zb = z / bdiv, zh = z % bdiv;
    A += (long)zb * sAb + (long)zh * sAh;
    B += (long)zb * sBb + (long)zh * sBh;
    const long coff = (long)zb * sCb + (long)zh * sCh;

    __shared__ ushort_t As[BM * BK];
    __shared__ ushort_t Bs[BN * BK];

    const int tid = threadIdx.x;
    const int w = tid >> 6, lane = tid & 63;
    const int wr = w / WN, wc = w % WN;
    const int m0 = blockIdx.y * BM;
    const int n0 = blockIdx.x * BN;

    f32x4 acc[MF][NF] = {};

    const int fr = lane & 15;
    const int kb = lane >> 4;

    for (int k0 = 0; k0 < K; k0 += BK) {
#pragma unroll
        for (int q = 0; q < (ACH + 3) / 4; ++q) {
            int ci = q * 4 + w;
            if (ci < ACH) {
                int e = ci * 512 + lane * 8;
                int r = e >> 5, c = e & 31;
                GLDS(A + (long)(m0 + r) * lda + (k0 + c), (char*)As + ci * 1024);
            }
        }
#pragma unroll
        for (int q = 0; q < (BCH + 3) / 4; ++q) {
            int ci = q * 4 + w;
            if (ci < BCH) {
                int e = ci * 512 + lane * 8;
                int r = e >> 5, c = e & 31;
                GLDS(B + (long)(n0 + r) * ldb + (k0 + c), (char*)Bs + ci * 1024);
            }
        }
        __syncthreads();

        short8 af[MF], bfr[NF];
#pragma unroll
        for (int fm = 0; fm < MF; ++fm)
            af[fm] = *(const short8*)&As[(wr * WTM + fm * 16 + fr) * 32 + kb * 8];
#pragma unroll
        for (int fn = 0; fn < NF; ++fn)
            bfr[fn] = *(const short8*)&Bs[(wc * WTN + fn * 16 + fr) * 32 + kb * 8];
#pragma unroll
        for (int fm = 0; fm < MF; ++fm)
#pragma unroll
            for (int fn = 0; fn < NF; ++fn)
                acc[fm][fn] = __builtin_amdgcn_mfma_f32_16x16x32_bf16(
                    af[fm], bfr[fn], acc[fm][fn], 0, 0, 0);
        __syncthreads();
    }

    const int cr = lane >> 4;
    const int cc = lane & 15;
#pragma unroll
    for (int fm = 0; fm < MF; ++fm) {
#pragma unroll
        for (int fn = 0; fn < NF; ++fn) {
#pragma unroll
            for (int j = 0; j < 4; ++j) {
                int gm = m0 + wr * WTM + fm * 16 + cr * 4 + j;
                int gn = n0 + wc * WTN + fn * 16 + cc;
                float v = alpha * acc[fm][fn][j];
                if (HASBIAS) v += bias[gn];
                if (GELU) v = 0.5f * v * (1.f + erff(v * 0.70710678118654752f));
                long idx = coff + (long)gm * ldc + gn;
                if (BETA) v += ((const float*)Cv)[idx];
                if (OUTBF) ((ushort_t*)Cv)[idx] = f2b(v);
                else       ((float*)Cv)[idx] = v;
            }
        }
    }
}

// ---------------------------------------------------------------------------
// kqv GEMM with scatter epilogue: A = xb (B*T*H, 96), B = Wkqv (288, 96).
// Writes K -> Kh[..,loff+n], Q*scale -> Qh[..,loff+n], V -> Vt[(bh,s),t].
// BM=128, BN=96 (block x: 0=K,1=Q,2=V uniformly), WM=4, WN=1. Grid (3,256).
// ---------------------------------------------------------------------------
__global__ __launch_bounds__(256) void kqv_gemm(
    const ushort_t* __restrict__ A,       // xb, lda 96
    const ushort_t* __restrict__ Bw,      // Wkqvb, ldb 96
    ushort_t* __restrict__ Kh, ushort_t* __restrict__ Qh,
    ushort_t* __restrict__ Vt, int loff, float scale)
{
    constexpr int BM = 128, BN = 96, BK = 32;
    __shared__ ushort_t As[BM * BK];
    __shared__ ushort_t Bs[BN * BK];

    const int tid = threadIdx.x;
    const int w = tid >> 6, lane = tid & 63;
    const int m0 = blockIdx.y * BM;
    const int n0 = blockIdx.x * BN;

    f32x4 acc[2][6] = {};
    const int fr = lane & 15;
    const int kb = lane >> 4;

    for (int k0 = 0; k0 < 96; k0 += BK) {
#pragma unroll
        for (int q = 0; q < 2; ++q) {
            int ci = q * 4 + w;
            int e = ci * 512 + lane * 8;
            int r = e >> 5, c = e & 31;
            GLDS(A + (long)(m0 + r) * ESS + (k0 + c), (char*)As + ci * 1024);
        }
        {
            int ci = w;      // 6 chunks: waves 0-3 then 2 more via second issue
            int e = ci * 512 + lane * 8;
            int r = e >> 5, c = e & 31;
            GLDS(Bw + (long)(n0 + r) * ESS + (k0 + c), (char*)Bs + ci * 1024);
            if (w < 2) {
                int ci2 = 4 + w;
                int e2 = ci2 * 512 + lane * 8;
                int r2 = e2 >> 5, c2 = e2 & 31;
                GLDS(Bw + (long)(n0 + r2) * ESS + (k0 + c2), (char*)Bs + ci2 * 1024);
            }
        }
        __syncthreads();

        short8 af[2], bfr[6];
#pragma unroll
        for (int fm = 0; fm < 2; ++fm)
            af[fm] = *(const short8*)&As[(w * 32 + fm * 16 + fr) * 32 + kb * 8];
#pragma unroll
        for (int fn = 0; fn < 6; ++fn)
            bfr[fn] = *(const short8*)&Bs[(fn * 16 + fr) * 32 + kb * 8];
#pragma unroll
        for (int fm = 0; fm < 2; ++fm)
#pragma unroll
            for (int fn = 0; fn < 6; ++fn)
                acc[fm][fn] = __builtin_amdgcn_mfma_f32_16x16x32_bf16(
                    af[fm], bfr[fn], acc[fm][fn], 0, 0, 0);
        __syncthreads();
    }

    const int cr = lane >> 4;
    const int cc = lane & 15;
    const int kind = blockIdx.x;      // 0 = K, 1 = Q, 2 = V
#pragma unroll
    for (int fm = 0; fm < 2; ++fm) {
#pragma unroll
        for (int fn = 0; fn < 6; ++fn) {
#pragma unroll
            for (int j = 0; j < 4; ++j) {
                int gm = m0 + w * 32 + fm * 16 + cr * 4 + j;
                int s = fn * 16 + cc;             // 0..95 within this kind
                float v = acc[fm][fn][j];
                int h = gm & 7;
                int bt = gm >> 3;                 // b*512 + t
                int t = bt & 511, b = bt >> 9;
                int bh = b * HH + h;
                if (kind == 0)
                    Kh[((long)(bh * TT + t)) * KHMAX + loff + s] = f2b(v);
                else if (kind == 1)
                    Qh[((long)(bh * TT + t)) * KHMAX + loff + s] = f2b(v * scale);
                else
                    Vt[((long)(bh * ESS + s)) * TT + t] = f2b(v);
            }
        }
    }
}

// ---------------------------------------------------------------------------
// Fused attention with Q/K-history accumulation (RealFormer carry).
// XCD-aware 1D grid (1024 blocks). R7 structure (best measured).
// Scale is pre-folded into Qh.
// ---------------------------------------------------------------------------
__global__ __launch_bounds__(256) void fused_attn(
    const ushort_t* __restrict__ Qh,    // (B*H, T, 576) bf16, cols [0,Kd)
    const ushort_t* __restrict__ Kh,    // (B*H, T, 576) bf16
    const ushort_t* __restrict__ Vt,    // (B*H, 96, T) bf16
    ushort_t* __restrict__ attn,        // (B,T,EMB) bf16
    int Kd)
{
    __shared__ char lds[40960];
    ushort_t* As = (ushort_t*)lds;              // 2 KiB: Q tile 32x32
    ushort_t* Bs = (ushort_t*)(lds + 2048);     // 32 KiB: K tile 512x32
    ushort_t* Pt = (ushort_t*)(lds + 2048);     // union: P 32x512 bf16 (swizzled)
    ushort_t* Vs = (ushort_t*)(lds + 34816);    // 6 KiB: V^T chunk 96x32
    float* red   = (float*)(lds + 34816);       // 512 B (union w/ Vs)
    float* red2  = (float*)(lds + 35328);       // 512 B

    // XCD swizzle: hw xcd = wg & 7 (round-robin)
    const int wg = blockIdx.x;
    const int xcd = wg & 7;
    const int sub = wg >> 3;          // 0..127, sequential within an XCD
    const int m0 = (sub & 15) * 32;   // m-tile fastest -> same bh consecutive
    const int bh = (sub >> 4) * 8 + xcd;
    const int b = bh >> 3, h = bh & 7;

    const int tid = threadIdx.x;
    const int w = tid >> 6, lane = tid & 63;
    const int fr = lane & 15, kb = lane >> 4;
    const int cr = kb, cc = fr;

    f32x4 acc[2][8] = {};

    // ---- phase 1: S = Q_hist K_hist^T over Kd feature cols ----
    for (int k0 = 0; k0 < Kd; k0 += 32) {
        if (w < 2) {
            int e = w * 512 + lane * 8;
            int r = e >> 5, c = e & 31;
            GLDS(Qh + ((long)(bh * TT + m0 + r)) * KHMAX + k0 + c,
                 (char*)As + w * 1024);
        }
#pragma unroll
        for (int q = 0; q < 8; ++q) {
            int ci = q * 4 + w;
            int e = ci * 512 + lane * 8;
            int r = e >> 5, c = e & 31;
            GLDS(Kh + ((long)(bh * TT + r)) * KHMAX + k0 + c,
                 (char*)Bs + ci * 1024);
        }
        __syncthreads();
        short8 af[2];
        af[0] = *(const short8*)&As[fr * 32 + kb * 8];
        af[1] = *(const short8*)&As[(16 + fr) * 32 + kb * 8];
#pragma unroll
        for (int fn = 0; fn < 8; ++fn) {
            short8 bf = *(const short8*)&Bs[(w * 128 + fn * 16 + fr) * 32 + kb * 8];
            acc[0][fn] = __builtin_amdgcn_mfma_f32_16x16x32_bf16(af[0], bf, acc[0][fn], 0, 0, 0);
            acc[1][fn] = __builtin_amdgcn_mfma_f32_16x16x32_bf16(af[1], bf, acc[1][fn], 0, 0, 0);
        }
        __syncthreads();
    }

    // ---- phase 2: softmax over key axis ----
#pragma unroll
    for (int fm = 0; fm < 2; ++fm)
#pragma unroll
        for (int j = 0; j < 4; ++j) {
            float mx = -1e30f;
#pragma unroll
            for (int fn = 0; fn < 8; ++fn) mx = fmaxf(mx, acc[fm][fn][j]);
            for (int o = 1; o <= 8; o <<= 1) mx = fmaxf(mx, __shfl_xor(mx, o));
            if (cc == 0) red[w * 32 + fm * 16 + cr * 4 + j] = mx;
        }
    __syncthreads();

    float inv[2][4];
#pragma unroll
    for (int fm = 0; fm < 2; ++fm)
#pragma unroll
        for (int j = 0; j < 4; ++j) {
            int r = fm * 16 + cr * 4 + j;
            float mx = fmaxf(fmaxf(red[r], red[32 + r]), fmaxf(red[64 + r], red[96 + r]));
            float s = 0.f;
#pragma unroll
            for (int fn = 0; fn < 8; ++fn) {
                float e = __expf(acc[fm][fn][j] - mx);
                acc[fm][fn][j] = e;
                s += e;
            }
            for (int o = 1; o <= 8; o <<= 1) s += __shfl_xor(s, o);
            if (cc == 0) red2[w * 32 + r] = s;
        }
    __syncthreads();
#pragma unroll
    for (int fm = 0; fm < 2; ++fm)
#pragma unroll
        for (int j = 0; j < 4; ++j) {
            int r = fm * 16 + cr * 4 + j;
            inv[fm][j] = 1.f / (red2[r] + red2[32 + r] + red2[64 + r] + red2[96 + r]);
        }

    // write P (bf16) into swizzled LDS tile (elem col ^= (row&7)<<3)
#pragma unroll
    for (int fm = 0; fm < 2; ++fm)
#pragma unroll
        for (int fn = 0; fn < 8; ++fn)
#pragma unroll
            for (int j = 0; j < 4; ++j) {
                int row = fm * 16 + cr * 4 + j;
                int col = w * 128 + fn * 16 + cc;
                Pt[row * 512 + (col ^ ((row & 7) << 3))] = f2b(acc[fm][fn][j] * inv[fm][j]);
            }
    __syncthreads();

    // ---- phase 3: attn = P @ V (LDS-staged V^T chunks) ----
    const int wr = w >> 1, wc2 = w & 1;
    f32x4 po[3] = {};
    for (int j0 = 0; j0 < TT; j0 += 32) {
#pragma unroll
        for (int q = 0; q < 2; ++q) {
            int ci = q * 4 + w;
            if (ci < 6) {
                int e = ci * 512 + lane * 8;
                int r = e >> 5, c = e & 31;
                GLDS(Vt + ((long)(bh * ESS + r)) * TT + j0 + c, (char*)Vs + ci * 1024);
            }
        }
        __syncthreads();
        int prow = wr * 16 + fr;
        short8 pa = *(const short8*)&Pt[prow * 512 + ((j0 + kb * 8) ^ ((prow & 7) << 3))];
#pragma unroll
        for (int fn = 0; fn < 3; ++fn) {
            short8 vb = *(const short8*)&Vs[(wc2 * 48 + fn * 16 + fr) * 32 + kb * 8];
            po[fn] = __builtin_amdgcn_mfma_f32_16x16x32_bf16(pa, vb, po[fn], 0, 0, 0);
        }
        __syncthreads();
    }

#pragma unroll
    for (int fn = 0; fn < 3; ++fn)
#pragma unroll
        for (int j = 0; j < 4; ++j) {
            int grow = m0 + wr * 16 + cr * 4 + j;
            int gcol = h * ESS + wc2 * 48 + fn * 16 + cc;
            attn[((long)(b * TT + grow)) * EMBD + gcol] = f2b(po[fn][j]);
        }
}

// ---------------------------------------------------------------------------
__global__ __launch_bounds__(256) void cvt_f2b(
    const float* __restrict__ in, ushort_t* __restrict__ out)
{
    const int i = blockIdx.x * 256 + threadIdx.x;
    float4 v = ((const float4*)in)[i];
    ushort4v o = {f2b(v.x), f2b(v.y), f2b(v.z), f2b(v.w)};
    ((ushort4v*)out)[i] = o;
}

// ---------------------------------------------------------------------------
// Weight conversion. Per-layer contiguous layout (float4/ushort4v units):
//   [wkqv 6912 | wproj 147456 | w1 589824 | w2 589824] = 1334016 per layer
// ---------------------------------------------------------------------------
static __device__ __forceinline__ void cvt_w_one(
    int r, int layer,
    const float* Wkqv, const float* Wproj, const float* w1, const float* w2,
    ushort_t* dst_layer)
{
    const float* src; int base;
    if (r < 6912)        { src = Wkqv  + (long)layer * 27648;   base = 0; }
    else if (r < 154368) { src = Wproj + (long)layer * 589824;  base = 6912; }
    else if (r < 744192) { src = w1    + (long)layer * 2359296; base = 154368; }
    else                 { src = w2    + (long)layer * 2359296; base = 744192; }
    int j = r - base;
    float4 v = ((const float4*)src)[j];
    ushort4v o = {f2b(v.x), f2b(v.y), f2b(v.z), f2b(v.w)};
    ((ushort4v*)dst_layer)[r] = o;
}

__global__ __launch_bounds__(256) void cvt_weights_all(
    const float* __restrict__ Wkqv, const float* __restrict__ Wproj,
    const float* __restrict__ w1, const float* __restrict__ w2,
    ushort_t* __restrict__ dst)      // 6 layers, stride 5336064 ushorts
{
    int i4 = blockIdx.x * 256 + threadIdx.x;    // 0 .. 8004095
    int layer = i4 / 1334016;
    int r = i4 - layer * 1334016;
    cvt_w_one(r, layer, Wkqv, Wproj, w1, w2, dst + (long)layer * 5336064);
}

__global__ __launch_bounds__(256) void cvt_weights_layer(
    const float* __restrict__ Wkqv, const float* __restrict__ Wproj,
    const float* __restrict__ w1, const float* __restrict__ w2,
    ushort_t* __restrict__ dst, int layer)      // one layer into dst
{
    int r = blockIdx.x * 256 + threadIdx.x;     // 0 .. 1334015
    cvt_w_one(r, layer, Wkqv, Wproj, w1, w2, dst);
}

// ---------------------------------------------------------------------------
// x = LayerNorm(x + r0 + r1 (+bias)) * g + b ; also emit bf16 copy.
// ---------------------------------------------------------------------------
__global__ __launch_bounds__(192) void add_ln(
    float* __restrict__ x, const float* __restrict__ r0,
    const float* __restrict__ r1, const float* __restrict__ bias,
    const float* __restrict__ g, const float* __restrict__ bta,
    ushort_t* __restrict__ xb)
{
    const long row = blockIdx.x;
    float4* xr = (float4*)(x + row * EMBD);
    const float4* q0 = (const float4*)(r0 + row * EMBD);
    const float4* q1 = (const float4*)(r1 + row * EMBD);
    __shared__ float sh[4];
    const int tid = threadIdx.x;
    const int lane = tid & 63, w = tid >> 6;

    float4 a = xr[tid], u0 = q0[tid], u1 = q1[tid];
    float v[4] = {a.x + u0.x + u1.x, a.y + u0.y + u1.y,
                  a.z + u0.z + u1.z, a.w + u0.w + u1.w};
    if (bias) {
        float4 b4 = ((const float4*)bias)[tid];
        v[0] += b4.x; v[1] += b4.y; v[2] += b4.z; v[3] += b4.w;
    }
    float s = v[0] + v[1] + v[2] + v[3];
    for (int o = 32; o; o >>= 1) s += __shfl_xor(s, o);
    if (lane == 0) sh[w] = s;
    __syncthreads();
    float mu = (sh[0] + sh[1] + sh[2]) * (1.f / EMBD);

    float var = 0.f;
#pragma unroll
    for (int c = 0; c < 4; ++c) { float d = v[c] - mu; var += d * d; }
    for (int o = 32; o; o >>= 1) var += __shfl_xor(var, o);
    __syncthreads();
    if (lane == 0) sh[w] = var;
    __syncthreads();
    var = (sh[0] + sh[1] + sh[2]) * (1.f / EMBD);
    float rstd = rsqrtf(var + 1e-5f);

    const float4 g4 = ((const float4*)g)[tid];
    const float4 b4 = ((const float4*)bta)[tid];
    float o0 = (v[0] - mu) * rstd * g4.x + b4.x;
    float o1 = (v[1] - mu) * rstd * g4.y + b4.y;
    float o2 = (v[2] - mu) * rstd * g4.z + b4.z;
    float o3 = (v[3] - mu) * rstd * g4.w + b4.w;
    float4 ov = {o0, o1, o2, o3};
    xr[tid] = ov;
    ushort4v ob = {f2b(o0), f2b(o1), f2b(o2), f2b(o3)};
    ((ushort4v*)(xb + row * EMBD))[tid] = ob;
}

// ---------------------------------------------------------------------------
extern "C" void kernel_launch(void* const* d_in, const int* in_sizes, int n_in,
                              void* d_out, int out_size, void* d_ws, size_t ws_size,
                              hipStream_t stream) {
    const float* x_in  = (const float*)d_in[0];
    const float* Wkqv  = (const float*)d_in[1];
    const float* Wproj = (const float*)d_in[2];
    const float* ln1_g = (const float*)d_in[3];
    const float* ln1_b = (const float*)d_in[4];
    const float* ln2_g = (const float*)d_in[5];
    const float* ln2_b = (const float*)d_in[6];
    const float* ff_w1 = (const float*)d_in[7];
    const float* ff_b1 = (const float*)d_in[8];
    const float* ff_w2 = (const float*)d_in[9];
    const float* ff_b2 = (const float*)d_in[10];

    float* x = (float*)d_out;
    char* ws = (char*)d_ws;
    ushort_t* Qh     = (ushort_t*)(ws);                   // 37.7 MB
    ushort_t* Kh     = (ushort_t*)(ws + 37748736);        // 37.7 MB
    ushort_t* Vtb    = (ushort_t*)(ws + 75497472);        // 6.3 MB
    float*    res0   = (float*)(ws + 75497472);           // 12.6 MB (union Vtb)
    float*    res1   = (float*)(ws + 88080384);           // 12.6 MB
    ushort_t* h1b    = (ushort_t*)(ws + 100663296);       // 25.2 MB
    ushort_t* xb     = (ushort_t*)(ws + 125829120);       // 6.3 MB
    ushort_t* attnb  = (ushort_t*)(ws + 132120576);       // 6.3 MB
    ushort_t* Wall   = (ushort_t*)(ws + 138412032);
    const size_t WLAYER_B = 10672128;          // bytes per layer slot
    const int    WLAYER_E = 5336064;           // ushorts per layer slot
    const int big = (ws_size >= 138412032 + 6 * WLAYER_B) ? 1 : 0;

    hipMemcpyAsync(x, x_in, (size_t)BB * TT * EMBD * sizeof(float),
                   hipMemcpyDeviceToDevice, stream);
    cvt_f2b<<<3072, 256, 0, stream>>>(x_in, xb);
    if (big)
        cvt_weights_all<<<31266, 256, 0, stream>>>(Wkqv, Wproj, ff_w1, ff_w2, Wall);

    const float scale = 0.10206207261596577f;  // 1/sqrt(96)

    for (int l = 0; l < NLAYER; ++l) {
        const float* b1 = ff_b1 + (size_t)l * FFD;
        const float* b2 = ff_b2 + (size_t)l * EMBD;

        ushort_t* Wl = Wall + (big ? (long)l * WLAYER_E : 0);
        if (!big)
            cvt_weights_layer<<<5211, 256, 0, stream>>>(Wkqv, Wproj, ff_w1, ff_w2, Wl, l);
        ushort_t* Wkqvb  = Wl;
        ushort_t* Wprojb = Wl + 27648;
        ushort_t* W1b    = Wl + 617472;
        ushort_t* W2b    = Wl + 2976768;

        // kqv GEMM with direct scatter epilogue: K,Q(scaled) -> history, V -> Vt
        kqv_gemm<<<dim3(3, 256, 1), 256, 0, stream>>>(
            xb, Wkqvb, Kh, Qh, Vtb, l * ESS, scale);

        // fused: S = Qh Kh^T (scale pre-folded, Kd=96*(l+1)); attn = softmax @ V
        fused_attn<<<1024, 256, 0, stream>>>(
            Qh, Kh, Vtb, attnb, ESS * (l + 1));

        // res0/res1 = attn @ Wproj^T split-K (Vtb dead)
        gemm_mfma<128, 128, 2, 2, 0, 0, 0, 0><<<dim3(6, 32, 2), 256, 0, stream>>>(
            attnb, EMBD, Wprojb, EMBD, res0, EMBD, EMBD / 2, 1.f, nullptr,
            1, 384, 0, 384, 0, (long)(res1 - res0), 0);

        add_ln<<<BB * TT, 192, 0, stream>>>(x, res0, res1, nullptr,
            ln1_g + (size_t)l * EMBD, ln1_b + (size_t)l * EMBD, xb);

        // h1 = gelu(xb @ W1^T + b1)
        gemm_mfma<128, 128, 2, 2, 1, 1, 1, 0><<<dim3(24, 32, 1), 256, 0, stream>>>(
            xb, EMBD, W1b, EMBD, h1b, FFD, EMBD, 1.f, b1,
            1, 0, 0, 0, 0, 0, 0);

        // res0/res1 = h1 @ W2^T split-K (b2 applied in ln2)
        gemm_mfma<128, 128, 2, 2, 0, 0, 0, 0><<<dim3(6, 32, 2), 256, 0, stream>>>(
            h1b, FFD, W2b, FFD, res0, EMBD, FFD / 2, 1.f, nullptr,
            1, 1536, 0, 1536, 0, (long)(res1 - res0), 0);

        add_ln<<<BB * TT, 192, 0, stream>>>(x, res0, res1, b2,
            ln2_g + (size_t)l * EMBD, ln2_b + (size_t)l * EMBD, xb);
    }
}